// Round 3
// baseline (511.198 us; speedup 1.0000x reference)
//
#include <hip/hip_runtime.h>

#define HW    (128*128)
#define DHW   (128*128*128)
#define NTOT  (4*DHW)
#define TX    64
#define TY    16
#define ZC    32
#define NPB0  8192        // P0 partial count (16*128*4 blocks)
#define NPT   256         // fused3 reduce-pass block count (16*4*4)

__device__ __forceinline__ float sigf(float x){ return 1.0f/(1.0f+__expf(-x)); }
__device__ __forceinline__ float4 ld4(const float* p){ return *(const float4*)p; }
__device__ __forceinline__ void st4(float* p, float4 q){ *(float4*)p = q; }

// ---------------------------------------------------------------------------
// P0: occupancy/surface/overhang partial sums + analytic resin-trap iter 1.
// block (32,8): thread = x-quad, y = blockIdx.x*8+ty, z = blockIdx.y
// ---------------------------------------------------------------------------
__global__ __launch_bounds__(256) void fused_first_k(
    const float* __restrict__ v, float* __restrict__ mask1,
    float* __restrict__ p_occ, float* __restrict__ p_surf,
    float* __restrict__ p_over)
{
    const int tx = threadIdx.x, ty = threadIdx.y;
    const int y = blockIdx.x*8 + ty;
    const int z = blockIdx.y;
    const int b = blockIdx.z;
    const int x4 = tx*4;
    const size_t idx = (size_t)b*DHW + ((size_t)z*128 + y)*128 + x4;

    float4 val = ld4(v + idx);
    float occ = val.x + val.y + val.z + val.w;

    float wz = (z==0 || z==127) ? 2.f : 3.f;
    float wy = (y==0 || y==127) ? 2.f : 3.f;
    float wx0 = (x4==0)     ? 2.f : 3.f;
    float wx3 = (x4+3==127) ? 2.f : 3.f;
    float surf = wz*wy*(wx0*val.x + 3.f*val.y + 3.f*val.z + wx3*val.w);

    float over = 0.f;
    if (z >= 1) {
        float4 s = make_float4(0,0,0,0);
        const float* below = v + idx - HW;
        #pragma unroll
        for (int dy = -1; dy <= 1; ++dy) {
            if ((unsigned)(y+dy) > 127u) continue;
            const float* row = below + dy*128;
            float4 q = ld4(row);
            float ql = (tx>0)  ? row[-1] : 0.f;
            float qr = (tx<31) ? row[4]  : 0.f;
            s.x += ql  + q.x + q.y;
            s.y += q.x + q.y + q.z;
            s.z += q.y + q.z + q.w;
            s.w += q.z + q.w + qr;
        }
        const float inv9 = 1.f/9.f;
        over = val.x*(1.f - s.x*inv9) + val.y*(1.f - s.y*inv9)
             + val.z*(1.f - s.z*inv9) + val.w*(1.f - s.w*inv9);
    }

    // analytic iteration 1 from seed at (5,5,5)
    const float a_hi = sigf(10.0f), a_lo = sigf(-10.0f);
    int dzy = abs(z-5) + abs(y-5);
    float4 m;
    {
        int d0 = dzy + abs(x4+0-5);
        int d1 = dzy + abs(x4+1-5);
        int d2 = dzy + abs(x4+2-5);
        int d3 = dzy + abs(x4+3-5);
        float p0 = (d0==0)?1.f:((d0==1)?a_hi:a_lo);
        float p1 = (d1==0)?1.f:((d1==1)?a_hi:a_lo);
        float p2 = (d2==0)?1.f:((d2==1)?a_hi:a_lo);
        float p3 = (d3==0)?1.f:((d3==1)?a_hi:a_lo);
        m = make_float4(p0*(1.f-val.x), p1*(1.f-val.y), p2*(1.f-val.z), p3*(1.f-val.w));
    }
    st4(mask1 + idx, m);

    __shared__ float sm[3][4];
    #pragma unroll
    for (int o = 32; o; o >>= 1) {
        occ  += __shfl_down(occ,  o, 64);
        surf += __shfl_down(surf, o, 64);
        over += __shfl_down(over, o, 64);
    }
    int tid = ty*32 + tx, lane = tid & 63, wid = tid >> 6;
    if (lane == 0) { sm[0][wid]=occ; sm[1][wid]=surf; sm[2][wid]=over; }
    __syncthreads();
    if (tid == 0) {
        int blin = (b*gridDim.y + blockIdx.y)*gridDim.x + blockIdx.x;
        p_occ [blin] = sm[0][0]+sm[0][1]+sm[0][2]+sm[0][3];
        p_surf[blin] = sm[1][0]+sm[1][1]+sm[1][2]+sm[1][3];
        p_over[blin] = sm[2][0]+sm[2][1]+sm[2][2]+sm[2][3];
    }
}

// ---------------------------------------------------------------------------
// Collapse P0 partials -> out[0] = overhang (final), out[1] = surf - occ_pen
// (trap term subtracted later by finalize_k). Runs BEFORE P1 clobbers maskB.
// ---------------------------------------------------------------------------
__global__ __launch_bounds__(1024) void collapse_k(
    const float* __restrict__ p_occ, const float* __restrict__ p_surf,
    const float* __restrict__ p_over, float* __restrict__ out)
{
    double occ=0, surf=0, over=0;
    for (int i = threadIdx.x; i < NPB0; i += 1024) {
        occ += p_occ[i]; surf += p_surf[i]; over += p_over[i];
    }
    __shared__ double sm[3][16];
    #pragma unroll
    for (int o = 32; o; o >>= 1) {
        occ  += __shfl_down(occ,  o, 64);
        surf += __shfl_down(surf, o, 64);
        over += __shfl_down(over, o, 64);
    }
    int lane = threadIdx.x & 63, wid = threadIdx.x >> 6;
    if (lane == 0) { sm[0][wid]=occ; sm[1][wid]=surf; sm[2][wid]=over; }
    __syncthreads();
    if (threadIdx.x == 0) {
        double so=0, ss=0, sv=0;
        for (int w = 0; w < 16; ++w) { so+=sm[0][w]; ss+=sm[1][w]; sv+=sm[2][w]; }
        double N = (double)NTOT;
        double occupancy = so / N;
        double occ_pen = 10.0 * (occupancy - 0.5) * (occupancy - 0.5);
        out[0] = (float)(sv / N);
        out[1] = (float)(ss / 27.0 / N - occ_pen);
    }
}

// ---------------------------------------------------------------------------
// fused3: 3 resin-trap iterations in one pass. z-wavefront with LDS rings.
// Tile TXxTY output, halo 3 in x/y/z. Stage0 (halo2) convs staged src planes;
// stage1 (halo1) convs stage0 ring; stage2 (halo0) convs stage1 ring and
// stores to dst, or (reduce mode, p_trap!=null) accumulates sum of iter 10.
// grid (16, 128/ZC, 4), block 512.
// ---------------------------------------------------------------------------
__global__ __launch_bounds__(512) void fused3_k(
    const float* __restrict__ src, float* __restrict__ dst,
    const float* __restrict__ v, float* __restrict__ p_trap)
{
    __shared__ float sS[3][22][72];   // src planes: ry -3..18, rx -3..66
    __shared__ float s0[3][22][72];   // stage0 out: ry -2..17, rx -2..65
    __shared__ float s1[3][22][72];   // stage1 out: ry -1..16, rx -1..64
    __shared__ float red[8];

    const int tid = threadIdx.x;
    const int x0 = (blockIdx.x & 1) * TX;
    const int y0 = (blockIdx.x >> 1) * TY;
    const int z0 = blockIdx.y * ZC;
    const int b  = blockIdx.z;
    const size_t gbase = (size_t)b * DHW;
    const bool reduce_mode = (p_trap != nullptr);
    float trap = 0.f;

    auto load_src = [&](int zs) {
        int sl = (zs + 3) % 3;
        bool zin = ((unsigned)zs < 128u);
        for (int i = tid; i < 70*22; i += 512) {
            int rx = i % 70 - 3, ry = i / 70 - 3;
            int x = x0 + rx, y = y0 + ry;
            float val = 0.f;
            if (zin && (unsigned)x < 128u && (unsigned)y < 128u)
                val = src[gbase + ((size_t)zs*128 + y)*128 + x];
            sS[sl][ry+3][rx+3] = val;
        }
    };

    // prefill src ring with planes z0-3, z0-2
    load_src(z0 - 3);
    load_src(z0 - 2);

    for (int m = 0; m <= ZC + 3; ++m) {
        const int za = z0 - 2 + m;          // stage0 plane
        const int zb = za - 1;              // stage1 plane
        const int zc = za - 2;              // stage2 plane

        load_src(za + 1);
        __syncthreads();                    // src ring ready

        // ---- stage 0: iter k, region 68x20 ----
        {
            int sl = (za + 3) % 3, smm = (za + 2) % 3, spp = (za + 4) % 3;
            bool zin = ((unsigned)za < 128u);
            for (int i = tid; i < 68*20; i += 512) {
                int rx = i % 68 - 2, ry = i / 68 - 2;
                int x = x0 + rx, y = y0 + ry;
                float val = 0.f;
                if (zin && (unsigned)x < 128u && (unsigned)y < 128u) {
                    float c = sS[smm][ry+3][rx+3] + sS[spp][ry+3][rx+3]
                            + sS[sl][ry+2][rx+3] + sS[sl][ry+4][rx+3]
                            + sS[sl][ry+3][rx+2] + sS[sl][ry+3][rx+4];
                    float ctr = sS[sl][ry+3][rx+3];
                    float vv = v[gbase + ((size_t)za*128 + y)*128 + x];
                    val = fmaxf(ctr, sigf(20.f*c - 10.f)) * (1.f - vv);
                }
                s0[sl][ry+3][rx+3] = val;
            }
        }
        __syncthreads();                    // stage0 ring ready

        // ---- stage 1: iter k+1, region 66x18 ----
        if (m >= 2) {
            int sl = (zb + 3) % 3, smm = (zb + 2) % 3, spp = (zb + 4) % 3;
            bool zin = ((unsigned)zb < 128u);
            for (int i = tid; i < 66*18; i += 512) {
                int rx = i % 66 - 1, ry = i / 66 - 1;
                int x = x0 + rx, y = y0 + ry;
                float val = 0.f;
                if (zin && (unsigned)x < 128u && (unsigned)y < 128u) {
                    float c = s0[smm][ry+3][rx+3] + s0[spp][ry+3][rx+3]
                            + s0[sl][ry+2][rx+3] + s0[sl][ry+4][rx+3]
                            + s0[sl][ry+3][rx+2] + s0[sl][ry+3][rx+4];
                    float ctr = s0[sl][ry+3][rx+3];
                    float vv = v[gbase + ((size_t)zb*128 + y)*128 + x];
                    val = fmaxf(ctr, sigf(20.f*c - 10.f)) * (1.f - vv);
                }
                s1[sl][ry+3][rx+3] = val;
            }
        }
        __syncthreads();                    // stage1 ring ready

        // ---- stage 2: iter k+2, region 64x16, store or reduce ----
        if (m >= 4) {
            int sl = (zc + 3) % 3, smm = (zc + 2) % 3, spp = (zc + 4) % 3;
            for (int i = tid; i < 64*16; i += 512) {
                int rx = i & 63, ry = i >> 6;
                int x = x0 + rx, y = y0 + ry;
                float c = s1[smm][ry+3][rx+3] + s1[spp][ry+3][rx+3]
                        + s1[sl][ry+2][rx+3] + s1[sl][ry+4][rx+3]
                        + s1[sl][ry+3][rx+2] + s1[sl][ry+3][rx+4];
                float ctr = s1[sl][ry+3][rx+3];
                size_t gi = gbase + ((size_t)zc*128 + y)*128 + x;
                float vv = v[gi];
                float val = fmaxf(ctr, sigf(20.f*c - 10.f)) * (1.f - vv);
                if (reduce_mode) trap += val;
                else             dst[gi] = val;
            }
        }
    }

    if (reduce_mode) {
        #pragma unroll
        for (int o = 32; o; o >>= 1) trap += __shfl_down(trap, o, 64);
        int lane = tid & 63, wid = tid >> 6;
        if (lane == 0) red[wid] = trap;
        __syncthreads();
        if (tid == 0) {
            float t = 0.f;
            #pragma unroll
            for (int w = 0; w < 8; ++w) t += red[w];
            int blin = (b*gridDim.y + blockIdx.y)*gridDim.x + blockIdx.x;
            p_trap[blin] = t;
        }
    }
}

// ---------------------------------------------------------------------------
// finalize: out[1] -= 100 * sum(trap partials) / N
// ---------------------------------------------------------------------------
__global__ __launch_bounds__(256) void finalize_k(
    const float* __restrict__ p_trap, float* __restrict__ out)
{
    double t = 0.0;
    for (int i = threadIdx.x; i < NPT; i += 256) t += p_trap[i];
    __shared__ double sm[4];
    #pragma unroll
    for (int o = 32; o; o >>= 1) t += __shfl_down(t, o, 64);
    int lane = threadIdx.x & 63, wid = threadIdx.x >> 6;
    if (lane == 0) sm[wid] = t;
    __syncthreads();
    if (threadIdx.x == 0) {
        double tt = sm[0] + sm[1] + sm[2] + sm[3];
        out[1] = (float)((double)out[1] - 100.0 * tt / (double)NTOT);
    }
}

extern "C" void kernel_launch(void* const* d_in, const int* in_sizes, int n_in,
                              void* d_out, int out_size, void* d_ws, size_t ws_size,
                              hipStream_t stream)
{
    const float* v = (const float*)d_in[0];
    float* out = (float*)d_out;
    char* ws = (char*)d_ws;

    // ws_size is exactly 2 * NTOT * 4 bytes. Partials live in maskB's tail:
    // P0 partials are consumed by collapse_k before P1 overwrites maskB;
    // trap partials are written by P3 after P2 has finished reading maskB.
    float* maskA = (float*)ws;
    float* maskB = (float*)(ws + (size_t)NTOT*4);
    float* p_occ  = maskB + NTOT - 3*NPB0;
    float* p_surf = p_occ + NPB0;
    float* p_over = p_surf + NPB0;
    float* p_trap = maskB + NTOT - NPT;

    dim3 blkA(32, 8, 1);
    dim3 grdA(16, 128, 4);
    dim3 grdF(16, 128/ZC, 4);

    // P0: reductions + analytic iteration-1 mask (one read of v)
    fused_first_k<<<grdA, blkA, 0, stream>>>(v, maskA, p_occ, p_surf, p_over);
    // collapse partials into d_out before maskB is overwritten
    collapse_k<<<1, 1024, 0, stream>>>(p_occ, p_surf, p_over, out);
    // iterations 2-4, 5-7, 8-10 (last pass reduces iter-10, no store)
    fused3_k<<<grdF, 512, 0, stream>>>(maskA, maskB, v, nullptr);
    fused3_k<<<grdF, 512, 0, stream>>>(maskB, maskA, v, nullptr);
    fused3_k<<<grdF, 512, 0, stream>>>(maskA, nullptr, v, p_trap);
    // subtract trap penalty
    finalize_k<<<1, 256, 0, stream>>>(p_trap, out);
}

// Round 4
// 129.864 us; speedup vs baseline: 3.9364x; 3.9364x over previous
//
#include <hip/hip_runtime.h>

#define HW    (128*128)
#define DHW   (128*128*128)
#define NTOT  (4*DHW)
#define NPB0  8192        // P0 partial count (16*128*4 blocks)
#define BS    16          // resin-trap sim box: cells [0,15]^3 (covers d<=10 from seed (5,5,5))
#define VB    17          // v box incl. +face halo: [0,16]^3

__device__ __forceinline__ float sigf(float x){ return 1.0f/(1.0f+__expf(-x)); }
__device__ __forceinline__ float4 ld4(const float* p){ return *(const float4*)p; }

// ---------------------------------------------------------------------------
// P0: occupancy / surface / overhang partial sums — one read of v, no writes
// except 96 KB of partials. block (32,8): thread = x-quad, y = bx*8+ty, z = by.
// surface: all-ones 3^3 conv total == coverage-weighted sum (2 at faces, 3 interior).
// ---------------------------------------------------------------------------
__global__ __launch_bounds__(256) void reduce_all_k(
    const float* __restrict__ v, float* __restrict__ p_occ,
    float* __restrict__ p_surf, float* __restrict__ p_over)
{
    const int tx = threadIdx.x, ty = threadIdx.y;
    const int y = blockIdx.x*8 + ty;
    const int z = blockIdx.y;
    const int b = blockIdx.z;
    const int x4 = tx*4;
    const size_t idx = (size_t)b*DHW + ((size_t)z*128 + y)*128 + x4;

    float4 val = ld4(v + idx);
    float occ = val.x + val.y + val.z + val.w;

    float wz = (z==0 || z==127) ? 2.f : 3.f;
    float wy = (y==0 || y==127) ? 2.f : 3.f;
    float wx0 = (x4==0)     ? 2.f : 3.f;
    float wx3 = (x4+3==127) ? 2.f : 3.f;
    float surf = wz*wy*(wx0*val.x + 3.f*val.y + 3.f*val.z + wx3*val.w);

    float over = 0.f;
    if (z >= 1) {
        float4 s = make_float4(0,0,0,0);
        const float* below = v + idx - HW;
        #pragma unroll
        for (int dy = -1; dy <= 1; ++dy) {
            if ((unsigned)(y+dy) > 127u) continue;
            const float* row = below + dy*128;
            float4 q = ld4(row);
            float ql = (tx>0)  ? row[-1] : 0.f;
            float qr = (tx<31) ? row[4]  : 0.f;
            s.x += ql  + q.x + q.y;
            s.y += q.x + q.y + q.z;
            s.z += q.y + q.z + q.w;
            s.w += q.z + q.w + qr;
        }
        const float inv9 = 1.f/9.f;
        over = val.x*(1.f - s.x*inv9) + val.y*(1.f - s.y*inv9)
             + val.z*(1.f - s.z*inv9) + val.w*(1.f - s.w*inv9);
    }

    __shared__ float sm[3][4];
    #pragma unroll
    for (int o = 32; o; o >>= 1) {
        occ  += __shfl_down(occ,  o, 64);
        surf += __shfl_down(surf, o, 64);
        over += __shfl_down(over, o, 64);
    }
    int tid = ty*32 + tx, lane = tid & 63, wid = tid >> 6;
    if (lane == 0) { sm[0][wid]=occ; sm[1][wid]=surf; sm[2][wid]=over; }
    __syncthreads();
    if (tid == 0) {
        int blin = (b*gridDim.y + blockIdx.y)*gridDim.x + blockIdx.x;
        p_occ [blin] = sm[0][0]+sm[0][1]+sm[0][2]+sm[0][3];
        p_surf[blin] = sm[1][0]+sm[1][1]+sm[1][2]+sm[1][3];
        p_over[blin] = sm[2][0]+sm[2][1]+sm[2][2]+sm[2][3];
    }
}

// ---------------------------------------------------------------------------
// Resin-trap box sim. Deviation from the background fixed point
// m_bg = a_lo*(1-v) is confined to Manhattan distance <= 10 from the seed
// (5,5,5), i.e. cells [0,15]^3. Simulate that box exactly (iterations 2..10,
// iteration 1 is analytic), with out-of-box in-grid neighbors taken at the
// background value (error O(a_lo*5e-3) in c -> utterly negligible) and
// out-of-grid neighbors = 0. Emit delta = sum(m10 - a_lo*(1-v)) per batch.
// block (16,16): thread (y,z) owns x-row [0,15] in registers. grid = 4 batches.
// ---------------------------------------------------------------------------
__global__ __launch_bounds__(256) void trap_box_k(
    const float* __restrict__ v, float* __restrict__ p_trap)
{
    __shared__ float vL[VB][VB][VB];   // [z][y][x], coords 0..16
    __shared__ float mL[BS][BS][BS];   // [z][y][x], coords 0..15
    __shared__ float red[4];

    const int b = blockIdx.x;
    const size_t gb = (size_t)b * DHW;
    const int y = threadIdx.x;
    const int z = threadIdx.y;
    const int tid = z*16 + y;

    for (int i = tid; i < VB*VB*VB; i += 256) {
        int x = i % VB, yy = (i / VB) % VB, zz = i / (VB*VB);
        vL[zz][yy][x] = v[gb + ((size_t)zz*128 + yy)*128 + x];
    }
    __syncthreads();

    const float a_lo = sigf(-10.0f);
    const float a_hi = sigf( 10.0f);

    float m[BS], nv[BS];
    {
        int dzy = abs(z-5) + abs(y-5);
        #pragma unroll
        for (int x = 0; x < BS; ++x) {
            nv[x] = 1.0f - vL[z][y][x];
            int d = dzy + abs(x-5);
            float pre = (d==0) ? 1.f : ((d==1) ? a_hi : a_lo);
            m[x] = pre * nv[x];
            mL[z][y][x] = m[x];
        }
    }

    // hoisted background terms at the +faces (only used by boundary threads)
    float bgx = a_lo * (1.0f - vL[z][y][16]);
    float bgy[BS], bgz[BS];
    #pragma unroll
    for (int x = 0; x < BS; ++x) {
        bgy[x] = a_lo * (1.0f - vL[z][16][x]);
        bgz[x] = a_lo * (1.0f - vL[16][y][x]);
    }
    __syncthreads();

    for (int it = 0; it < 9; ++it) {
        float nm[BS];
        #pragma unroll
        for (int x = 0; x < BS; ++x) {
            float c = (x > 0  ? m[x-1] : 0.f)
                    + (x < 15 ? m[x+1] : bgx)
                    + (y > 0  ? mL[z][y-1][x] : 0.f)
                    + (y < 15 ? mL[z][y+1][x] : bgy[x])
                    + (z > 0  ? mL[z-1][y][x] : 0.f)
                    + (z < 15 ? mL[z+1][y][x] : bgz[x]);
            nm[x] = fmaxf(m[x], sigf(20.f*c - 10.f)) * nv[x];
        }
        __syncthreads();          // all reads of mL done
        #pragma unroll
        for (int x = 0; x < BS; ++x) { m[x] = nm[x]; mL[z][y][x] = nm[x]; }
        __syncthreads();
    }

    float d = 0.f;
    #pragma unroll
    for (int x = 0; x < BS; ++x) d += m[x] - a_lo * nv[x];
    #pragma unroll
    for (int o = 32; o; o >>= 1) d += __shfl_down(d, o, 64);
    int lane = tid & 63, wid = tid >> 6;
    if (lane == 0) red[wid] = d;
    __syncthreads();
    if (tid == 0) p_trap[b] = red[0] + red[1] + red[2] + red[3];
}

// ---------------------------------------------------------------------------
// finalize: combine everything.
// trap_sum = a_lo*(N - sum(v)) + sum(box deltas)
// ---------------------------------------------------------------------------
__global__ __launch_bounds__(1024) void finalize_k(
    const float* __restrict__ p_occ, const float* __restrict__ p_surf,
    const float* __restrict__ p_over, const float* __restrict__ p_trap,
    float* __restrict__ out)
{
    double occ=0, surf=0, over=0;
    for (int i = threadIdx.x; i < NPB0; i += 1024) {
        occ += p_occ[i]; surf += p_surf[i]; over += p_over[i];
    }
    __shared__ double sm[3][16];
    #pragma unroll
    for (int o = 32; o; o >>= 1) {
        occ  += __shfl_down(occ,  o, 64);
        surf += __shfl_down(surf, o, 64);
        over += __shfl_down(over, o, 64);
    }
    int lane = threadIdx.x & 63, wid = threadIdx.x >> 6;
    if (lane == 0) { sm[0][wid]=occ; sm[1][wid]=surf; sm[2][wid]=over; }
    __syncthreads();
    if (threadIdx.x == 0) {
        double so=0, ss=0, sv=0;
        for (int w = 0; w < 16; ++w) { so+=sm[0][w]; ss+=sm[1][w]; sv+=sm[2][w]; }
        double dS = (double)p_trap[0] + p_trap[1] + p_trap[2] + p_trap[3];
        double a_lo = (double)sigf(-10.0f);
        double N = (double)NTOT;
        double trap_sum = a_lo * (N - so) + dS;
        double occupancy = so / N;
        double occ_pen = 10.0 * (occupancy - 0.5) * (occupancy - 0.5);
        out[0] = (float)(sv / N);
        out[1] = (float)(ss / 27.0 / N - 100.0 * trap_sum / N - occ_pen);
    }
}

extern "C" void kernel_launch(void* const* d_in, const int* in_sizes, int n_in,
                              void* d_out, int out_size, void* d_ws, size_t ws_size,
                              hipStream_t stream)
{
    const float* v = (const float*)d_in[0];
    float* out = (float*)d_out;
    float* ws = (float*)d_ws;

    float* p_occ  = ws;
    float* p_surf = p_occ  + NPB0;
    float* p_over = p_surf + NPB0;
    float* p_trap = p_over + NPB0;   // 4 floats

    dim3 blkA(32, 8, 1);
    dim3 grdA(16, 128, 4);

    reduce_all_k<<<grdA, blkA, 0, stream>>>(v, p_occ, p_surf, p_over);
    trap_box_k<<<4, dim3(16,16,1), 0, stream>>>(v, p_trap);
    finalize_k<<<1, 1024, 0, stream>>>(p_occ, p_surf, p_over, p_trap, out);
}

// Round 6
// 108.285 us; speedup vs baseline: 4.7209x; 1.1993x over previous
//
#include <hip/hip_runtime.h>

#define HW    (128*128)
#define DHW   (128*128*128)
#define NTOT  (4*DHW)
#define NPB0  8192        // reduce_all partial count (16*128*4 blocks)
#define BS    16          // resin-trap sim box: cells [0,15]^3 (covers d<=10 from seed (5,5,5))
#define MPAD  17          // LDS x-stride pad: bank=(272z+17y+x)%32 -> 2-way across 64 lanes (free)

__device__ __forceinline__ float sigf(float x){ return 1.0f/(1.0f+__expf(-x)); }
__device__ __forceinline__ float4 ld4(const float* p){ return *(const float4*)p; }

// ---------------------------------------------------------------------------
// P0: occupancy / surface / overhang partial sums — one read of v.
// block (32,8): thread = x-quad, y = bx*8+ty, z = by.
// surface: all-ones 3^3 conv total == coverage-weighted sum (2 at faces, 3 interior).
// overhang 3x3 row sums: quad-edge neighbors via __shfl (the lanes where the
// shuffle crosses a ty-row are exactly the masked x4==0 / x4+3==127 lanes).
// ---------------------------------------------------------------------------
__global__ __launch_bounds__(256) void reduce_all_k(
    const float* __restrict__ v, float* __restrict__ p_occ,
    float* __restrict__ p_surf, float* __restrict__ p_over)
{
    const int tx = threadIdx.x, ty = threadIdx.y;
    const int y = blockIdx.x*8 + ty;
    const int z = blockIdx.y;
    const int b = blockIdx.z;
    const int x4 = tx*4;
    const size_t idx = (size_t)b*DHW + ((size_t)z*128 + y)*128 + x4;

    float4 val = ld4(v + idx);
    float occ = val.x + val.y + val.z + val.w;

    float wz = (z==0 || z==127) ? 2.f : 3.f;
    float wy = (y==0 || y==127) ? 2.f : 3.f;
    float wx0 = (x4==0)     ? 2.f : 3.f;
    float wx3 = (x4+3==127) ? 2.f : 3.f;
    float surf = wz*wy*(wx0*val.x + 3.f*val.y + 3.f*val.z + wx3*val.w);

    float over = 0.f;
    if (z >= 1) {
        const float4 zero = make_float4(0,0,0,0);
        const float* below = v + idx - HW;
        float4 s = zero;
        #pragma unroll
        for (int dy = -1; dy <= 1; ++dy) {
            float4 q = ((unsigned)(y+dy) <= 127u) ? ld4(below + dy*128) : zero;
            float ql = __shfl_up(q.w, 1);     // prev quad's .w (same ty row except masked lane)
            float qr = __shfl_down(q.x, 1);   // next quad's .x
            if (x4 == 0)   ql = 0.f;
            if (x4 == 124) qr = 0.f;
            s.x += ql  + q.x + q.y;
            s.y += q.x + q.y + q.z;
            s.z += q.y + q.z + q.w;
            s.w += q.z + q.w + qr;
        }
        const float inv9 = 1.f/9.f;
        over = val.x*(1.f - s.x*inv9) + val.y*(1.f - s.y*inv9)
             + val.z*(1.f - s.z*inv9) + val.w*(1.f - s.w*inv9);
    }

    __shared__ float sm[3][4];
    #pragma unroll
    for (int o = 32; o; o >>= 1) {
        occ  += __shfl_down(occ,  o, 64);
        surf += __shfl_down(surf, o, 64);
        over += __shfl_down(over, o, 64);
    }
    int tid = ty*32 + tx, lane = tid & 63, wid = tid >> 6;
    if (lane == 0) { sm[0][wid]=occ; sm[1][wid]=surf; sm[2][wid]=over; }
    __syncthreads();
    if (tid == 0) {
        int blin = (b*gridDim.y + blockIdx.y)*gridDim.x + blockIdx.x;
        p_occ [blin] = sm[0][0]+sm[0][1]+sm[0][2]+sm[0][3];
        p_surf[blin] = sm[1][0]+sm[1][1]+sm[1][2]+sm[1][3];
        p_over[blin] = sm[2][0]+sm[2][1]+sm[2][2]+sm[2][3];
    }
}

// ---------------------------------------------------------------------------
// Resin-trap box sim. Deviation from the background fixed point
// m_bg = a_lo*(1-v) is confined to Manhattan distance <= 10 from the seed
// (5,5,5), i.e. cells [0,15]^3. Simulate that box exactly (iteration 1 is
// analytic; 9 more iterations), +face neighbors at background value,
// out-of-grid neighbors = 0. Emit delta = sum(m10 - a_lo*(1-v)) per batch.
// block (16,16): thread (y,z) owns x-row [0,15]; v in registers; mask in
// ping-pong padded LDS; one barrier per iteration.
// JACOBI DISCIPLINE: new values go to nm[] / nxt only; m[] is updated after
// the full x-sweep (in-loop m[x]=nm made it Gauss-Seidel -> R5 failure).
// grid = 4 batches.
// ---------------------------------------------------------------------------
__global__ __launch_bounds__(256) void trap_box_k(
    const float* __restrict__ v, float* __restrict__ p_trap)
{
    __shared__ float mA[BS][BS][MPAD];
    __shared__ float mB[BS][BS][MPAD];
    __shared__ float red[4];

    const int b = blockIdx.x;
    const size_t gb = (size_t)b * DHW;
    const int y = threadIdx.x;
    const int z = threadIdx.y;
    const int tid = z*16 + y;

    const float a_lo = sigf(-10.0f);
    const float a_hi = sigf( 10.0f);

    // v rows straight to registers (no LDS staging)
    const float* rowv = v + gb + ((size_t)z*128 + y)*128;   // v[z][y][0..]
    const float* rowy = v + gb + ((size_t)z*128 + 16)*128;  // v[z][16][0..]
    const float* rowz = v + gb + ((size_t)16*128 + y)*128;  // v[16][y][0..]
    float nv[BS], bgy[BS], bgz[BS];
    #pragma unroll
    for (int q = 0; q < 4; ++q) {
        float4 a = ld4(rowv + 4*q);
        float4 c = ld4(rowy + 4*q);
        float4 d = ld4(rowz + 4*q);
        nv [4*q+0]=1.f-a.x; nv [4*q+1]=1.f-a.y; nv [4*q+2]=1.f-a.z; nv [4*q+3]=1.f-a.w;
        bgy[4*q+0]=a_lo*(1.f-c.x); bgy[4*q+1]=a_lo*(1.f-c.y); bgy[4*q+2]=a_lo*(1.f-c.z); bgy[4*q+3]=a_lo*(1.f-c.w);
        bgz[4*q+0]=a_lo*(1.f-d.x); bgz[4*q+1]=a_lo*(1.f-d.y); bgz[4*q+2]=a_lo*(1.f-d.z); bgz[4*q+3]=a_lo*(1.f-d.w);
    }
    const float bgx = a_lo * (1.f - rowv[16]);

    // analytic iteration 1 from seed at (5,5,5)
    float m[BS];
    {
        int dzy = abs(z-5) + abs(y-5);
        #pragma unroll
        for (int x = 0; x < BS; ++x) {
            int d = dzy + abs(x-5);
            float pre = (d==0) ? 1.f : ((d==1) ? a_hi : a_lo);
            m[x] = pre * nv[x];
            mA[z][y][x] = m[x];
        }
    }
    __syncthreads();

    const float* cur = &mA[0][0][0];
    float*       nxt = &mB[0][0][0];
    for (int it = 0; it < 9; ++it) {
        const float* rym = cur + ((z*BS + (y-1))*MPAD);
        const float* ryp = cur + ((z*BS + (y+1))*MPAD);
        const float* rzm = cur + (((z-1)*BS + y)*MPAD);
        const float* rzp = cur + (((z+1)*BS + y)*MPAD);
        float* wrow = nxt + ((z*BS + y)*MPAD);
        float nm[BS];
        #pragma unroll
        for (int x = 0; x < BS; ++x) {
            float c = (x > 0  ? m[x-1] : 0.f)
                    + (x < 15 ? m[x+1] : bgx)
                    + (y > 0  ? rym[x] : 0.f)
                    + (y < 15 ? ryp[x] : bgy[x])
                    + (z > 0  ? rzm[x] : 0.f)
                    + (z < 15 ? rzp[x] : bgz[x]);
            nm[x] = fmaxf(m[x], sigf(20.f*c - 10.f)) * nv[x];
            wrow[x] = nm[x];            // nxt buffer: no one reads it this iter
        }
        #pragma unroll
        for (int x = 0; x < BS; ++x) m[x] = nm[x];   // Jacobi update AFTER sweep
        __syncthreads();
        const float* t = cur; cur = nxt; nxt = (float*)t;
    }

    float d = 0.f;
    #pragma unroll
    for (int x = 0; x < BS; ++x) d += m[x] - a_lo * nv[x];
    #pragma unroll
    for (int o = 32; o; o >>= 1) d += __shfl_down(d, o, 64);
    int lane = tid & 63, wid = tid >> 6;
    if (lane == 0) red[wid] = d;
    __syncthreads();
    if (tid == 0) p_trap[b] = red[0] + red[1] + red[2] + red[3];
}

// ---------------------------------------------------------------------------
// finalize: combine everything.
// trap_sum = a_lo*(N - sum(v)) + sum(box deltas)
// ---------------------------------------------------------------------------
__global__ __launch_bounds__(1024) void finalize_k(
    const float* __restrict__ p_occ, const float* __restrict__ p_surf,
    const float* __restrict__ p_over, const float* __restrict__ p_trap,
    float* __restrict__ out)
{
    double occ=0, surf=0, over=0;
    for (int i = threadIdx.x; i < NPB0; i += 1024) {
        occ += p_occ[i]; surf += p_surf[i]; over += p_over[i];
    }
    __shared__ double sm[3][16];
    #pragma unroll
    for (int o = 32; o; o >>= 1) {
        occ  += __shfl_down(occ,  o, 64);
        surf += __shfl_down(surf, o, 64);
        over += __shfl_down(over, o, 64);
    }
    int lane = threadIdx.x & 63, wid = threadIdx.x >> 6;
    if (lane == 0) { sm[0][wid]=occ; sm[1][wid]=surf; sm[2][wid]=over; }
    __syncthreads();
    if (threadIdx.x == 0) {
        double so=0, ss=0, sv=0;
        for (int w = 0; w < 16; ++w) { so+=sm[0][w]; ss+=sm[1][w]; sv+=sm[2][w]; }
        double dS = (double)p_trap[0] + p_trap[1] + p_trap[2] + p_trap[3];
        double a_lo = (double)sigf(-10.0f);
        double N = (double)NTOT;
        double trap_sum = a_lo * (N - so) + dS;
        double occupancy = so / N;
        double occ_pen = 10.0 * (occupancy - 0.5) * (occupancy - 0.5);
        out[0] = (float)(sv / N);
        out[1] = (float)(ss / 27.0 / N - 100.0 * trap_sum / N - occ_pen);
    }
}

extern "C" void kernel_launch(void* const* d_in, const int* in_sizes, int n_in,
                              void* d_out, int out_size, void* d_ws, size_t ws_size,
                              hipStream_t stream)
{
    const float* v = (const float*)d_in[0];
    float* out = (float*)d_out;
    float* ws = (float*)d_ws;

    float* p_occ  = ws;
    float* p_surf = p_occ  + NPB0;
    float* p_over = p_surf + NPB0;
    float* p_trap = p_over + NPB0;   // 4 floats

    dim3 blkA(32, 8, 1);
    dim3 grdA(16, 128, 4);

    trap_box_k<<<4, dim3(16,16,1), 0, stream>>>(v, p_trap);
    reduce_all_k<<<grdA, blkA, 0, stream>>>(v, p_occ, p_surf, p_over);
    finalize_k<<<1, 1024, 0, stream>>>(p_occ, p_surf, p_over, p_trap, out);
}